// Round 7
// baseline (564.378 us; speedup 1.0000x reference)
//
#include <hip/hip_runtime.h>
#include <hip/hip_fp16.h>
#include <cstdint>
#include <cstddef>

typedef _Float16 f16x8 __attribute__((ext_vector_type(8)));
typedef _Float16 f16x4 __attribute__((ext_vector_type(4)));
typedef float    f32x4 __attribute__((ext_vector_type(4)));

// ---------------------------------------------------------------------------
// fake-quant with fractional bit-width interpolation (matches jax reference)
// ---------------------------------------------------------------------------
__device__ __forceinline__ float quant_interp(float v, float alpha) {
    float a    = fmaxf(alpha, 1.0f);
    float blo  = floorf(a);
    float frac = a - blo;
    float slo  = exp2f(blo) - 1.0f;
    float shi  = 2.0f * slo + 1.0f;
    float rslo = __builtin_amdgcn_rcpf(slo);
    float rshi = __builtin_amdgcn_rcpf(shi);
    float c    = fminf(fmaxf(v, -1.0f), 1.0f);
    float qlo  = rintf(c * slo) * rslo;
    float qhi  = rintf(c * shi) * rshi;
    return (1.0f - frac) * qlo + frac * qhi;
}

// ---------------------------------------------------------------------------
// column mean of alpha_a [OUT][IN] -> a_feat [IN], deterministic two-pass
// ---------------------------------------------------------------------------
__global__ void colsum_partial_kernel(const float* __restrict__ aA,
                                      float* __restrict__ partial,
                                      int IN, int rows_per) {
    int col = blockIdx.x * blockDim.x + threadIdx.x;
    size_t r0 = (size_t)blockIdx.y * rows_per;
    float s = 0.f;
    for (int r = 0; r < rows_per; ++r)
        s += aA[(r0 + r) * (size_t)IN + col];
    partial[(size_t)blockIdx.y * IN + col] = s;
}

__global__ void colsum_final_kernel(const float* __restrict__ partial,
                                    float* __restrict__ afeat,
                                    int IN, int nchunk, float inv) {
    int col = blockIdx.x * blockDim.x + threadIdx.x;
    float s = 0.f;
    for (int c = 0; c < nchunk; ++c)
        s += partial[(size_t)c * IN + col];
    afeat[col] = s * inv;
}

// ---------------------------------------------------------------------------
// quantize x [M][IN] with per-column alpha -> fp16
// ---------------------------------------------------------------------------
__global__ void quant_x_kernel(const float* __restrict__ x,
                               const float* __restrict__ afeat,
                               f16x4* __restrict__ qx, int IN, size_t n4) {
    size_t i = (size_t)blockIdx.x * blockDim.x + threadIdx.x;
    size_t stride = (size_t)gridDim.x * blockDim.x;
    for (; i < n4; i += stride) {
        size_t e = i * 4;
        int col = (int)(e % (size_t)IN);
        f32x4 xv = *(const f32x4*)(x + e);
        f32x4 av = *(const f32x4*)(afeat + col);
        f16x4 o;
        #pragma unroll
        for (int j = 0; j < 4; ++j) o[j] = (_Float16)quant_interp(xv[j], av[j]);
        qx[i] = o;
    }
}

__global__ void quant_w_kernel(const float* __restrict__ w,
                               const float* __restrict__ aw,
                               f16x4* __restrict__ qw, size_t n4) {
    size_t i = (size_t)blockIdx.x * blockDim.x + threadIdx.x;
    size_t stride = (size_t)gridDim.x * blockDim.x;
    for (; i < n4; i += stride) {
        f32x4 wv = *(const f32x4*)(w + i * 4);
        f32x4 av = *(const f32x4*)(aw + i * 4);
        f16x4 o;
        #pragma unroll
        for (int j = 0; j < 4; ++j) o[j] = (_Float16)quant_interp(wv[j], av[j]);
        qw[i] = o;
    }
}

// ---------------------------------------------------------------------------
// 256x256 NT GEMM, fp16 in / fp32 out. "A-DIRECT" structure:
//   A fragments load straight global->VGPR (no LDS): addr = row*K + kt*64 +
//   (ks*4+hi)*8 halfs; per instruction 16 rows x 64B contiguous (full-line
//   coalesced); A is L3-resident (64MB) so re-reads don't hit HBM.
//   B is LDS-staged (double-buffered, XOR-swizzled, global_load_lds w=16).
//   Wave grid 4(M) x 2(N): wave tile 64x128 -> A-frags depend on wm
//   (2x dup via wn only); B dup handled by LDS.
//   Per-CU/K-tile pipe budget: MFMA 2483 cyc; LDS = 64KB reads + 32KB
//   writes ~= 1000 cyc (was ~2800 when A went through LDS -- THE R6 wall);
//   A via L2 ~= 64KB ~= 1100 cyc. Every pipe now under the MFMA floor.
//   ONE barrier + ONE vmcnt(0) per tile (B-stage flight = full tile ~2500
//   cyc >> 900 cyc HBM latency -> drain is free). Compiler handles A's RAW
//   with counted vmcnt and B's with counted lgkmcnt (no manual drains
//   before MFMA -- the R3/R5 lockstep mistake).
//   WAR: stage B(t+1)->nbuf; nbuf last read at tile t-1, reads retired by
//   compiler waits before t-1's MFMAs, hence before the end-of-(t-1)
//   barrier -> 1-barrier separation. Gates/barriers are asm with "memory"
//   clobber so reads/stages can't cross the sync point.
// ---------------------------------------------------------------------------
__device__ __forceinline__ void gload_lds16(const void* g, void* l) {
    __builtin_amdgcn_global_load_lds(
        (const __attribute__((address_space(1))) void*)g,
        (__attribute__((address_space(3))) void*)l, 16, 0, 0);
}

__device__ __forceinline__ f16x8 lds_frag(const _Float16* buf, int row, int ks, int hi) {
    const int sl = (ks * 4 + hi) ^ (row & 7);
    return *(const f16x8*)((const char*)buf + row * 128 + sl * 16);
}

#define GATE0()  asm volatile("s_waitcnt vmcnt(0)" ::: "memory")
#define BAR()    asm volatile("s_barrier" ::: "memory")

__global__ __launch_bounds__(512, 2) void gemm_ad_kernel(
    const _Float16* __restrict__ A,   // [M][K] qx
    const _Float16* __restrict__ B,   // [N][K] qw
    const float* __restrict__ bias,   // [N]
    float* __restrict__ C,            // [M][N]
    int M, int N, int K)
{
    constexpr int BK = 64;
    __shared__ _Float16 sB[2][256 * BK];   // 2 x 32 KiB

    const int tid  = (int)threadIdx.x;
    const int lane = tid & 63;
    const int wave = tid >> 6;
    const int wm   = wave >> 1;    // 0..3 (M quarter)
    const int wn   = wave & 1;     // 0..1 (N half)
    const int r15  = lane & 15;
    const int hi   = lane >> 4;

    const int nbx = N >> 8;
    const int nwg = (M >> 8) * nbx;
    const int bid = (int)blockIdx.x;
    const int swz = (nwg & 7) ? bid : ((bid & 7) * (nwg >> 3) + (bid >> 3));
    const size_t bm0 = (size_t)(swz / nbx) << 8;
    const size_t bn0 = (size_t)(swz % nbx) << 8;

    const int nkt = K / BK;
    const _Float16* Bgb = B + bn0 * K;
    // per-lane A base: rows bm0 + wm*64 + mi*16 + r15
    const _Float16* Agb = A + (bm0 + (size_t)(wm * 64 + r15)) * K;

    // stage one B half-tile (128 rows x 64 halfs): half 0 or 1
    auto STAGE_B = [&](int tile, int half) {
        if (tile >= nkt) return;
        const _Float16* g = Bgb + (size_t)tile * BK;
        _Float16* lb = sB[tile & 1];
        const int rb = half << 7;
        #pragma unroll
        for (int rr = 0; rr < 2; ++rr) {
            const int row = rb + rr * 64 + (tid >> 3);
            const int sg  = (tid & 7) ^ (row & 7);
            gload_lds16(g + (size_t)row * K + sg * 8,
                        (char*)lb + ((rb + rr * 64) << 7) + (wave << 10));
        }
    };

    f32x4 acc[4][8] = {};
    f16x8 af[4][2], bf[4][2];

    // prologue: stage tile0's B fully; one-time drain
    STAGE_B(0, 0); STAGE_B(0, 1);
    GATE0(); BAR();

    for (int t = 0; t < nkt; ++t) {
        const _Float16* Bb = sB[t & 1];

        // A fragments: direct global->VGPR (counted vmcnt handles RAW)
        #pragma unroll
        for (int mi = 0; mi < 4; ++mi)
            #pragma unroll
            for (int ks = 0; ks < 2; ++ks)
                af[mi][ks] = *(const f16x8*)(Agb + (size_t)(mi * 16) * K +
                                             (size_t)t * BK + (ks * 4 + hi) * 8);

        // B first half (cols wn*128 .. +63)
        #pragma unroll
        for (int nf = 0; nf < 4; ++nf) {
            const int row = wn * 128 + nf * 16 + r15;
            bf[nf][0] = lds_frag(Bb, row, 0, hi);
            bf[nf][1] = lds_frag(Bb, row, 1, hi);
        }

        // stage next tile's B into the other buffer
        STAGE_B(t + 1, 0); STAGE_B(t + 1, 1);

        __builtin_amdgcn_s_setprio(1);
        #pragma unroll
        for (int mi = 0; mi < 4; ++mi)
            #pragma unroll
            for (int nf = 0; nf < 4; ++nf) {
                f32x4& ac = acc[mi][nf];
                ac = __builtin_amdgcn_mfma_f32_16x16x32_f16(af[mi][0], bf[nf][0], ac, 0, 0, 0);
                ac = __builtin_amdgcn_mfma_f32_16x16x32_f16(af[mi][1], bf[nf][1], ac, 0, 0, 0);
            }
        __builtin_amdgcn_s_setprio(0);

        // B second half (cols wn*128+64 .. +127), reuse bf regs
        #pragma unroll
        for (int nf = 0; nf < 4; ++nf) {
            const int row = wn * 128 + 64 + nf * 16 + r15;
            bf[nf][0] = lds_frag(Bb, row, 0, hi);
            bf[nf][1] = lds_frag(Bb, row, 1, hi);
        }

        __builtin_amdgcn_s_setprio(1);
        #pragma unroll
        for (int mi = 0; mi < 4; ++mi)
            #pragma unroll
            for (int nf = 0; nf < 4; ++nf) {
                f32x4& ac = acc[mi][4 + nf];
                ac = __builtin_amdgcn_mfma_f32_16x16x32_f16(af[mi][0], bf[nf][0], ac, 0, 0, 0);
                ac = __builtin_amdgcn_mfma_f32_16x16x32_f16(af[mi][1], bf[nf][1], ac, 0, 0, 0);
            }
        __builtin_amdgcn_s_setprio(0);

        // tile boundary: B(t+1) staged a full tile ago -> free drain; publish
        GATE0(); BAR();
    }

    // epilogue: C/D layout col = lane&15, row = (lane>>4)*4 + reg
    #pragma unroll
    for (int nf = 0; nf < 8; ++nf) {
        const size_t col = bn0 + (size_t)(wn * 128 + nf * 16 + r15);
        const float bv = bias[col];
        #pragma unroll
        for (int mi = 0; mi < 4; ++mi) {
            const size_t row0 = bm0 + (size_t)(wm * 64 + mi * 16 + hi * 4);
            #pragma unroll
            for (int r = 0; r < 4; ++r)
                C[(row0 + r) * N + col] = acc[mi][nf][r] + bv;
        }
    }
}

// ---------------------------------------------------------------------------
extern "C" void kernel_launch(void* const* d_in, const int* in_sizes, int n_in,
                              void* d_out, int out_size, void* d_ws, size_t ws_size,
                              hipStream_t stream) {
    const float* x    = (const float*)d_in[0];
    const float* w    = (const float*)d_in[1];
    const float* bias = (const float*)d_in[2];
    const float* aw   = (const float*)d_in[3];
    const float* aA   = (const float*)d_in[4];

    const int    OUT = in_sizes[2];
    const size_t wsz = (size_t)in_sizes[1];
    const int    IN  = (int)(wsz / OUT);
    const int    M   = in_sizes[0] / IN;    // 8192
    const int    N   = OUT;                 // 4096
    const int    K   = IN;                  // 4096

    char* ws = (char*)d_ws;
    _Float16* qx = (_Float16*)ws;                                   // M*K*2
    _Float16* qw = (_Float16*)(ws + (size_t)M * K * 2);             // N*K*2
    float* afeat   = (float*)(ws + (size_t)M * K * 2 + (size_t)N * K * 2);
    float* partial = afeat + K;                                     // 32*K

    const int NCHUNK = 32;
    dim3 g1(K / 256, NCHUNK);
    colsum_partial_kernel<<<g1, 256, 0, stream>>>(aA, partial, K, OUT / NCHUNK);
    colsum_final_kernel<<<K / 256, 256, 0, stream>>>(partial, afeat, K, NCHUNK,
                                                     1.0f / (float)OUT);

    quant_x_kernel<<<2048, 256, 0, stream>>>(x, afeat, (f16x4*)qx, K,
                                             (size_t)M * K / 4);
    quant_w_kernel<<<2048, 256, 0, stream>>>(w, aw, (f16x4*)qw,
                                             (size_t)N * K / 4);

    const int nwg = (M / 256) * (N / 256);
    gemm_ad_kernel<<<nwg, 512, 0, stream>>>(qx, qw, bias, (float*)d_out,
                                            M, N, K);
}

// Round 8
// 514.610 us; speedup vs baseline: 1.0967x; 1.0967x over previous
//
#include <hip/hip_runtime.h>
#include <hip/hip_fp16.h>
#include <cstdint>
#include <cstddef>

typedef _Float16 f16x8 __attribute__((ext_vector_type(8)));
typedef _Float16 f16x4 __attribute__((ext_vector_type(4)));
typedef float    f32x4 __attribute__((ext_vector_type(4)));

// ---------------------------------------------------------------------------
// fake-quant with fractional bit-width interpolation (matches jax reference)
// ---------------------------------------------------------------------------
__device__ __forceinline__ float quant_interp(float v, float alpha) {
    float a    = fmaxf(alpha, 1.0f);
    float blo  = floorf(a);
    float frac = a - blo;
    float slo  = exp2f(blo) - 1.0f;
    float shi  = 2.0f * slo + 1.0f;
    float rslo = __builtin_amdgcn_rcpf(slo);
    float rshi = __builtin_amdgcn_rcpf(shi);
    float c    = fminf(fmaxf(v, -1.0f), 1.0f);
    float qlo  = rintf(c * slo) * rslo;
    float qhi  = rintf(c * shi) * rshi;
    return qlo + frac * (qhi - qlo);
}

// ---------------------------------------------------------------------------
// column mean of alpha_a [OUT][IN] -> a_feat [IN], deterministic two-pass
// ---------------------------------------------------------------------------
__global__ void colsum_partial_kernel(const float* __restrict__ aA,
                                      float* __restrict__ partial,
                                      int IN, int rows_per) {
    int col = blockIdx.x * blockDim.x + threadIdx.x;
    size_t r0 = (size_t)blockIdx.y * rows_per;
    float s = 0.f;
    for (int r = 0; r < rows_per; ++r)
        s += aA[(r0 + r) * (size_t)IN + col];
    partial[(size_t)blockIdx.y * IN + col] = s;
}

__global__ void colsum_final_kernel(const float* __restrict__ partial,
                                    float* __restrict__ afeat,
                                    int IN, int nchunk, float inv) {
    int col = blockIdx.x * blockDim.x + threadIdx.x;
    float s = 0.f;
    for (int c = 0; c < nchunk; ++c)
        s += partial[(size_t)c * IN + col];
    afeat[col] = s * inv;
}

// ---------------------------------------------------------------------------
// quantize x [M][K] -> qx in MFMA-FRAGMENT-TILED layout:
//   group index i enumerates (m16, k32, hi, r):  i = ((m16*K32 + k32)*4+hi)*16+r
//   group i holds halfs A[m16*16+r][k32*32 + hi*8 .. +8]  (16B, lane order)
// GEMM then loads af[mf][ks] as ONE coalesced dwordx4: 64 lanes x 16B
// contiguous (the R7 A-direct idea minus the 64-line stride catastrophe).
// Input reads stay wave-coalesced: a wave covers rows 0..15 x 128B segments.
// ---------------------------------------------------------------------------
__global__ void quant_x_tiled_kernel(const float* __restrict__ x,
                                     const float* __restrict__ afeat,
                                     f16x8* __restrict__ qx,
                                     int K, unsigned ngroups) {
    const int K32 = K >> 5;
    unsigned i = blockIdx.x * blockDim.x + threadIdx.x;
    const unsigned stride = gridDim.x * blockDim.x;
    for (; i < ngroups; i += stride) {
        const int r   = i & 15;
        const int hi  = (i >> 4) & 3;
        const unsigned rest = i >> 6;
        const int k32 = (int)(rest % (unsigned)K32);
        const unsigned m16 = rest / (unsigned)K32;
        const size_t row = (size_t)m16 * 16 + r;
        const int kb = k32 * 32 + hi * 8;
        const float* xp = x + row * K + kb;
        f32x4 x0 = *(const f32x4*)xp;
        f32x4 x1 = *(const f32x4*)(xp + 4);
        f32x4 a0 = *(const f32x4*)(afeat + kb);
        f32x4 a1 = *(const f32x4*)(afeat + kb + 4);
        f16x8 o;
        #pragma unroll
        for (int j = 0; j < 4; ++j) o[j]     = (_Float16)quant_interp(x0[j], a0[j]);
        #pragma unroll
        for (int j = 0; j < 4; ++j) o[4 + j] = (_Float16)quant_interp(x1[j], a1[j]);
        qx[i] = o;
    }
}

__global__ void quant_w_kernel(const float* __restrict__ w,
                               const float* __restrict__ aw,
                               f16x4* __restrict__ qw, size_t n4) {
    size_t i = (size_t)blockIdx.x * blockDim.x + threadIdx.x;
    size_t stride = (size_t)gridDim.x * blockDim.x;
    for (; i < n4; i += stride) {
        f32x4 wv = *(const f32x4*)(w + i * 4);
        f32x4 av = *(const f32x4*)(aw + i * 4);
        f16x4 o;
        #pragma unroll
        for (int j = 0; j < 4; ++j) o[j] = (_Float16)quant_interp(wv[j], av[j]);
        qw[i] = o;
    }
}

// ---------------------------------------------------------------------------
// 256x256 NT GEMM, fp16 in / fp32 out. "A-TILED-DIRECT" structure:
//   A: fragment-tiled global layout -> af[mf][ks] is one coalesced
//      global_load_dwordx4 straight to VGPR (no LDS, no barrier coupling;
//      compiler handles RAW with counted vmcnt and can float loads across
//      MFMA clusters). A re-read (4x dup across wn) = 128KB/CU/tile from
//      L2/L3 ~= 955 cyc < MFMA floor 2483 cyc.
//   B: R6's proven LDS path: double-buffered, XOR-swizzled (phys slot =
//      logical ^ (row&7), inverse pre-applied to the GLOBAL source, linear
//      LDS dest -- rule #21), global_load_lds w=16, distance-1 staging.
//      LDS pipe now only 64KB reads + 32KB writes /tile ~= 1000 cyc.
//   Sync: ONE vmcnt(0) + ONE barrier per K-tile (R6 skeleton, best so far);
//   no pre-MFMA drains -- compiler emits counted lgkmcnt per MFMA dep.
//   8 waves = 2(M) x 4(N); wave tile 128x64; acc[8][4] f32x4; MFMA split in
//   two mh-clusters so af[4][2] registers are reused (VGPR budget ~215).
// ---------------------------------------------------------------------------
__device__ __forceinline__ void gload_lds16(const void* g, void* l) {
    __builtin_amdgcn_global_load_lds(
        (const __attribute__((address_space(1))) void*)g,
        (__attribute__((address_space(3))) void*)l, 16, 0, 0);
}

__device__ __forceinline__ f16x8 lds_frag(const _Float16* buf, int row, int ks, int hi) {
    const int sl = (ks * 4 + hi) ^ (row & 7);
    return *(const f16x8*)((const char*)buf + row * 128 + sl * 16);
}

#define GATE0()  asm volatile("s_waitcnt vmcnt(0)" ::: "memory")
#define BAR()    asm volatile("s_barrier" ::: "memory")

__global__ __launch_bounds__(512, 2) void gemm_atd_kernel(
    const _Float16* __restrict__ Aq,  // fragment-tiled qx
    const _Float16* __restrict__ B,   // [N][K] qw
    const float* __restrict__ bias,   // [N]
    float* __restrict__ C,            // [M][N]
    int M, int N, int K)
{
    constexpr int BK = 64;
    __shared__ _Float16 sB[2][256 * BK];   // 2 x 32 KiB

    const int tid  = (int)threadIdx.x;
    const int lane = tid & 63;
    const int wave = tid >> 6;
    const int wm   = wave >> 2;    // 0..1
    const int wn   = wave & 3;     // 0..3
    const int r15  = lane & 15;
    const int hi   = lane >> 4;

    const int nbx = N >> 8;
    const int nwg = (M >> 8) * nbx;
    const int bid = (int)blockIdx.x;
    const int swz = (nwg & 7) ? bid : ((bid & 7) * (nwg >> 3) + (bid >> 3));
    const size_t bm0 = (size_t)(swz / nbx) << 8;
    const size_t bn0 = (size_t)(swz % nbx) << 8;

    const int nkt = K / BK;
    const int K32 = K >> 5;
    const _Float16* Bgb = B + bn0 * K;
    // A fragment-chunk base: chunk (m16, c) lives at ((m16*K32 + c) * 512
    // halfs); lane offset = lane*8 halfs. m16 per frag mf:
    //   rows (mf>>2)*128 + wm*64 + (mf&3)*16  ->  m16 = (mf>>2)*8+wm*4+(mf&3)
    const _Float16* Alane = Aq + (size_t)lane * 8;
    const size_t m16b = (bm0 >> 4);

    // stage B tile (256 rows x 64 halfs = 32KB): 4 gload_lds per block
    auto STAGE_B = [&](int tile) {
        if (tile >= nkt) return;
        const _Float16* g = Bgb + (size_t)tile * BK;
        _Float16* lb = sB[tile & 1];
        #pragma unroll
        for (int rr = 0; rr < 4; ++rr) {
            const int row = rr * 64 + (tid >> 3);
            const int sg  = (tid & 7) ^ (row & 7);
            gload_lds16(g + (size_t)row * K + sg * 8,
                        (char*)lb + ((rr * 64) << 7) + (wave << 10));
        }
    };

    f32x4 acc[8][4] = {};
    f16x8 af[4][2], bf[4][2];

    // prologue: stage tile0's B; one-time drain
    STAGE_B(0);
    GATE0(); BAR();

    for (int t = 0; t < nkt; ++t) {
        const _Float16* Bb = sB[t & 1];

        // A loads for mh=0 (coalesced dwordx4 -> VGPR)
        #pragma unroll
        for (int mi = 0; mi < 4; ++mi) {
            const size_t m16 = m16b + wm * 4 + mi;
            #pragma unroll
            for (int ks = 0; ks < 2; ++ks)
                af[mi][ks] = *(const f16x8*)(Alane +
                             ((m16 * K32 + (size_t)(t * 2 + ks)) << 9));
        }
        // B fragments (8 x ds_read_b128, register-resident for whole tile)
        #pragma unroll
        for (int nf = 0; nf < 4; ++nf) {
            const int row = (nf >> 1) * 128 + wn * 32 + (nf & 1) * 16 + r15;
            bf[nf][0] = lds_frag(Bb, row, 0, hi);
            bf[nf][1] = lds_frag(Bb, row, 1, hi);
        }
        // stage next tile's B into the other buffer
        STAGE_B(t + 1);

        __builtin_amdgcn_s_setprio(1);
        #pragma unroll
        for (int mi = 0; mi < 4; ++mi)
            #pragma unroll
            for (int nf = 0; nf < 4; ++nf) {
                f32x4& ac = acc[mi][nf];
                ac = __builtin_amdgcn_mfma_f32_16x16x32_f16(af[mi][0], bf[nf][0], ac, 0, 0, 0);
                ac = __builtin_amdgcn_mfma_f32_16x16x32_f16(af[mi][1], bf[nf][1], ac, 0, 0, 0);
            }
        __builtin_amdgcn_s_setprio(0);

        // A loads for mh=1 (reuse af regs; compiler may pre-hoist)
        #pragma unroll
        for (int mi = 0; mi < 4; ++mi) {
            const size_t m16 = m16b + 8 + wm * 4 + mi;
            #pragma unroll
            for (int ks = 0; ks < 2; ++ks)
                af[mi][ks] = *(const f16x8*)(Alane +
                             ((m16 * K32 + (size_t)(t * 2 + ks)) << 9));
        }

        __builtin_amdgcn_s_setprio(1);
        #pragma unroll
        for (int mi = 0; mi < 4; ++mi)
            #pragma unroll
            for (int nf = 0; nf < 4; ++nf) {
                f32x4& ac = acc[4 + mi][nf];
                ac = __builtin_amdgcn_mfma_f32_16x16x32_f16(af[mi][0], bf[nf][0], ac, 0, 0, 0);
                ac = __builtin_amdgcn_mfma_f32_16x16x32_f16(af[mi][1], bf[nf][1], ac, 0, 0, 0);
            }
        __builtin_amdgcn_s_setprio(0);

        // tile boundary: B(t+1) staged ~a full tile ago -> near-free drain
        GATE0(); BAR();
    }

    // epilogue: C/D layout col = lane&15, row = (lane>>4)*4 + reg
    #pragma unroll
    for (int nf = 0; nf < 4; ++nf) {
        const size_t col = bn0 + (size_t)((nf >> 1) * 128 + wn * 32 + (nf & 1) * 16 + r15);
        const float bv = bias[col];
        #pragma unroll
        for (int mf = 0; mf < 8; ++mf) {
            const size_t row0 = bm0 + (size_t)((mf >> 2) * 128 + wm * 64 + (mf & 3) * 16 + hi * 4);
            #pragma unroll
            for (int r = 0; r < 4; ++r)
                C[(row0 + r) * N + col] = acc[mf][nf][r] + bv;
        }
    }
}

// ---------------------------------------------------------------------------
extern "C" void kernel_launch(void* const* d_in, const int* in_sizes, int n_in,
                              void* d_out, int out_size, void* d_ws, size_t ws_size,
                              hipStream_t stream) {
    const float* x    = (const float*)d_in[0];
    const float* w    = (const float*)d_in[1];
    const float* bias = (const float*)d_in[2];
    const float* aw   = (const float*)d_in[3];
    const float* aA   = (const float*)d_in[4];

    const int    OUT = in_sizes[2];
    const size_t wsz = (size_t)in_sizes[1];
    const int    IN  = (int)(wsz / OUT);
    const int    M   = in_sizes[0] / IN;    // 8192
    const int    N   = OUT;                 // 4096
    const int    K   = IN;                  // 4096

    char* ws = (char*)d_ws;
    _Float16* qx = (_Float16*)ws;                                   // M*K*2 (tiled)
    _Float16* qw = (_Float16*)(ws + (size_t)M * K * 2);             // N*K*2
    float* afeat   = (float*)(ws + (size_t)M * K * 2 + (size_t)N * K * 2);
    float* partial = afeat + K;                                     // 32*K

    const int NCHUNK = 32;
    dim3 g1(K / 256, NCHUNK);
    colsum_partial_kernel<<<g1, 256, 0, stream>>>(aA, partial, K, OUT / NCHUNK);
    colsum_final_kernel<<<K / 256, 256, 0, stream>>>(partial, afeat, K, NCHUNK,
                                                     1.0f / (float)OUT);

    const unsigned ngroups = (unsigned)((size_t)M * K / 8);
    quant_x_tiled_kernel<<<2048, 256, 0, stream>>>(x, afeat, (f16x8*)qx, K,
                                                   ngroups);
    quant_w_kernel<<<2048, 256, 0, stream>>>(w, aw, (f16x4*)qw,
                                             (size_t)N * K / 4);

    const int nwg = (M / 256) * (N / 256);
    gemm_atd_kernel<<<nwg, 512, 0, stream>>>(qx, qw, bias, (float*)d_out,
                                             M, N, K);
}